// Round 5
// baseline (282.835 us; speedup 1.0000x reference)
//
#include <hip/hip_runtime.h>

// ---------------------------------------------------------------------------
// MultiHeadAttention (B=2, S=2048, D=1024, H=16, dk=64) on gfx950
// R5: flash_attn restructured: S computed TRANSPOSED (A=K, B=Q) so the
//     score/p registers are directly the B-fragment of mfma_16x16x16_bf16
//     for PV -> P LDS roundtrip eliminated (was ~40% of LDS pipe).
//     XOR-swizzled K/V tiles (no pad), 2-wave blocks, LDS-staged epilogue.
// ---------------------------------------------------------------------------

typedef __bf16 bf16_8 __attribute__((ext_vector_type(8)));
typedef __bf16 bf16_4 __attribute__((ext_vector_type(4)));
typedef float  f32x4  __attribute__((ext_vector_type(4)));

#define MFMA16(a, b, c) __builtin_amdgcn_mfma_f32_16x16x32_bf16((a), (b), (c), 0, 0, 0)

#if __has_builtin(__builtin_amdgcn_mfma_f32_16x16x16_bf16)
#define MFMA_PV(a, b, c) __builtin_amdgcn_mfma_f32_16x16x16_bf16((a), (b), (c), 0, 0, 0)
#elif __has_builtin(__builtin_amdgcn_mfma_f32_16x16x16bf16_1k)
typedef short s16x4 __attribute__((ext_vector_type(4)));
#define MFMA_PV(a, b, c)                                                  \
  __builtin_amdgcn_mfma_f32_16x16x16bf16_1k(                              \
      __builtin_bit_cast(s16x4, (a)), __builtin_bit_cast(s16x4, (b)), (c), 0, 0, 0)
#else
static __device__ __forceinline__ f32x4 mfma_pv_asm(bf16_4 a, bf16_4 b, f32x4 c) {
  asm volatile("v_mfma_f32_16x16x16_bf16 %0, %1, %2, %0\n\ts_nop 3"
               : "+v"(c) : "v"(a), "v"(b));
  return c;
}
#define MFMA_PV(a, b, c) mfma_pv_asm((a), (b), (c))
#endif

__device__ __forceinline__ void async_ld16(const void* g, void* l) {
  __builtin_amdgcn_global_load_lds(
      (__attribute__((address_space(1))) void*)g,
      (__attribute__((address_space(3))) void*)l, 16, 0, 0);
}

// ---------------------------------------------------------------------------
// 128x128 GEMM core (m97 structure), BK=32, A [MxK] rm, BT [NxK] rm.
// ---------------------------------------------------------------------------
__device__ __forceinline__ void gemm_core_128(
    const __bf16* __restrict__ A, const __bf16* __restrict__ BT, int K,
    int tm, int tn, __bf16* At, __bf16* Bt, f32x4 acc[4][4]) {
  const int tid  = threadIdx.x;
  const int lane = tid & 63;
  const int w    = tid >> 6;
  const int quad = lane >> 4;
  const int c16  = lane & 15;
  const int wm = w >> 1, wn = w & 1;

  const int ch0  = w * 2;
  const int row0 = ch0 * 16 + (lane >> 2);
  const int col0 = (lane & 3) * 8;
  const __bf16* Ag = A  + (size_t)(tm + row0) * K + col0;
  const __bf16* Bg = BT + (size_t)(tn + row0) * K + col0;
  __bf16* Al = At + ch0 * 512;
  __bf16* Bl = Bt + ch0 * 512;
  const size_t rowK16 = (size_t)16 * K;

  for (int kt = 0; kt < K; kt += 32) {
    async_ld16(Ag + kt,          Al);
    async_ld16(Ag + rowK16 + kt, Al + 512);
    async_ld16(Bg + kt,          Bl);
    async_ld16(Bg + rowK16 + kt, Bl + 512);
    __syncthreads();

    bf16_8 af[4], bfr[4];
#pragma unroll
    for (int mi = 0; mi < 4; ++mi)
      af[mi] = *(const bf16_8*)(At + (wm * 64 + mi * 16 + c16) * 32 + quad * 8);
#pragma unroll
    for (int ni = 0; ni < 4; ++ni)
      bfr[ni] = *(const bf16_8*)(Bt + (wn * 64 + ni * 16 + c16) * 32 + quad * 8);
#pragma unroll
    for (int mi = 0; mi < 4; ++mi)
#pragma unroll
      for (int ni = 0; ni < 4; ++ni)
        acc[mi][ni] = MFMA16(af[mi], bfr[ni], acc[mi][ni]);
    __syncthreads();
  }
}

// ---------------------------------------------------------------------------
// Fused QKV projection. grid = (256,1,3). V produced transposed [B,H,64,S].
// Q output pre-scaled by 1/sqrt(dk)=0.125.
// ---------------------------------------------------------------------------
__global__ __launch_bounds__(256)
void qkv_fused(const __bf16* __restrict__ xq, const __bf16* __restrict__ xk,
               const __bf16* __restrict__ xv,
               const __bf16* __restrict__ wq, const __bf16* __restrict__ wk,
               const __bf16* __restrict__ wv,
               const float* __restrict__ bq, const float* __restrict__ bk,
               const float* __restrict__ bv,
               __bf16* __restrict__ Qo, __bf16* __restrict__ Ko,
               __bf16* __restrict__ Vo) {
  __shared__ __bf16 At[128 * 32];
  __shared__ __bf16 Bt[128 * 32];
  const int z  = blockIdx.z;
  const int bx = blockIdx.x;
  const __bf16 *A, *BT;
  const float* bias;
  int tm, tn;
  if (z == 2) {        // V^T: M=1024 feats, N=4096 tokens
    A = wv; BT = xv; bias = bv;
    tm = (bx >> 5) * 128; tn = (bx & 31) * 128;
  } else if (z == 1) {
    A = xk; BT = wk; bias = bk;
    tm = (bx >> 3) * 128; tn = (bx & 7) * 128;
  } else {
    A = xq; BT = wq; bias = bq;
    tm = (bx >> 3) * 128; tn = (bx & 7) * 128;
  }

  f32x4 acc[4][4];
  const f32x4 zero4 = {0.f, 0.f, 0.f, 0.f};
#pragma unroll
  for (int i = 0; i < 4; ++i)
#pragma unroll
    for (int j = 0; j < 4; ++j) acc[i][j] = zero4;

  gemm_core_128(A, BT, 1024, tm, tn, At, Bt, acc);

  const int lane = threadIdx.x & 63;
  const int w    = threadIdx.x >> 6;
  const int quad = lane >> 4, c16 = lane & 15;
  const int wm = w >> 1, wn = w & 1;

  if (z == 2) {
#pragma unroll
    for (int mi = 0; mi < 4; ++mi) {
#pragma unroll
      for (int ni = 0; ni < 4; ++ni) {
        const int n  = tn + wn * 64 + ni * 16 + c16;  // token
        const int bb = n >> 11, s = n & 2047;
#pragma unroll
        for (int r = 0; r < 4; ++r) {
          const int m  = tm + wm * 64 + mi * 16 + quad * 4 + r;  // feature
          const int hh = m >> 6, d = m & 63;
          Vo[(((size_t)(bb * 16 + hh) * 64 + d) << 11) + s] =
              (__bf16)(acc[mi][ni][r] + bias[m]);
        }
      }
    }
  } else {
    __bf16* Out = (z == 1) ? Ko : Qo;
    const float scale = (z == 0) ? 0.125f : 1.0f;
#pragma unroll
    for (int mi = 0; mi < 4; ++mi) {
#pragma unroll
      for (int ni = 0; ni < 4; ++ni) {
        const int n  = tn + wn * 64 + ni * 16 + c16;  // feature
        const int hh = n >> 6, d = n & 63;
        const float bn = bias[n];
#pragma unroll
        for (int r = 0; r < 4; ++r) {
          const int m  = tm + wm * 64 + mi * 16 + quad * 4 + r;  // token
          const int bb = m >> 11, s = m & 2047;
          Out[(((size_t)(bb * 16 + hh) * 2048 + s) << 6) + d] =
              (__bf16)((acc[mi][ni][r] + bn) * scale);
        }
      }
    }
  }
}

// ---------------------------------------------------------------------------
// Output projection, 64x128 tile -> 512 blocks.
// ---------------------------------------------------------------------------
__global__ __launch_bounds__(256)
void out_proj(const __bf16* __restrict__ ctx, const __bf16* __restrict__ wo,
              const float* __restrict__ bo, float* __restrict__ out) {
  __shared__ __bf16 At[64 * 32];
  __shared__ __bf16 Bt[128 * 32];
  const int bx = blockIdx.x;
  const int tm = (bx >> 3) * 64, tn = (bx & 7) * 128;

  const int tid  = threadIdx.x;
  const int lane = tid & 63, w = tid >> 6;
  const int quad = lane >> 4, c16 = lane & 15;
  const int wm = w >> 1, wn = w & 1;

  const int row0 = lane >> 2, col0 = (lane & 3) * 8;
  const __bf16* Ag = ctx + (size_t)(tm + w * 16 + row0) * 1024 + col0;
  const __bf16* Bg = wo  + (size_t)(tn + w * 32 + row0) * 1024 + col0;
  __bf16* Al = At + w * 512;
  __bf16* Bl = Bt + w * 1024;

  f32x4 acc[2][4];
  const f32x4 zero4 = {0.f, 0.f, 0.f, 0.f};
#pragma unroll
  for (int i = 0; i < 2; ++i)
#pragma unroll
    for (int j = 0; j < 4; ++j) acc[i][j] = zero4;

  for (int kt = 0; kt < 1024; kt += 32) {
    async_ld16(Ag + kt, Al);
    async_ld16(Bg + kt, Bl);
    async_ld16(Bg + 16 * 1024 + kt, Bl + 512);
    __syncthreads();

    bf16_8 af[2], bfr[4];
#pragma unroll
    for (int mi = 0; mi < 2; ++mi)
      af[mi] = *(const bf16_8*)(At + (wm * 32 + mi * 16 + c16) * 32 + quad * 8);
#pragma unroll
    for (int ni = 0; ni < 4; ++ni)
      bfr[ni] = *(const bf16_8*)(Bt + (wn * 64 + ni * 16 + c16) * 32 + quad * 8);
#pragma unroll
    for (int mi = 0; mi < 2; ++mi)
#pragma unroll
      for (int ni = 0; ni < 4; ++ni)
        acc[mi][ni] = MFMA16(af[mi], bfr[ni], acc[mi][ni]);
    __syncthreads();
  }

#pragma unroll
  for (int mi = 0; mi < 2; ++mi) {
#pragma unroll
    for (int ni = 0; ni < 4; ++ni) {
      const int n = tn + wn * 64 + ni * 16 + c16;
      const float bn = bo[n];
#pragma unroll
      for (int r = 0; r < 4; ++r) {
        const int m = tm + wm * 32 + mi * 16 + quad * 4 + r;
        out[(size_t)m * 1024 + n] = acc[mi][ni][r] + bn;
      }
    }
  }
}

// ---------------------------------------------------------------------------
// Flash attention, transposed-S scheme. grid = (32,16,2), 128 thr (2 waves).
// Wave = 32 q-rows. K tile [64 key][64 d], V^T tile [64 d][64 key] in LDS,
// XOR-swizzled 16B chunks (chunk ^= row&7), stride 64, no pad.
// S^T = K·Q^T via mfma_16x16x32 (A=K-frag, B=Q-frag) -> D[key=quad*4+r][q=c16].
// p = exp2(fma(s,log2e,maskadd)) packed bf16x4 == B-frag of mfma_16x16x16.
// O^T[d][q] += V^T-frag · p  -- no P LDS roundtrip, no shuffles in loop.
// Deferred softmax (fixed -12 shift); lsum per-lane, 4-lane reduce at end.
// Epilogue: normalize, transpose via (now free) K/V LDS, 16B stores.
// ---------------------------------------------------------------------------
__global__ __launch_bounds__(128)
void flash_attn(const __bf16* __restrict__ Qg, const __bf16* __restrict__ Kg,
                const __bf16* __restrict__ VTg, const int* __restrict__ maskg,
                __bf16* __restrict__ ctx) {
  __shared__ __bf16 KV[8192];          // Kl = KV[0..4096), Vl = KV[4096..8192)
  __shared__ alignas(16) float maskadd[64];
  __bf16* Kl = KV;
  __bf16* Vl = KV + 4096;

  const int t    = threadIdx.x;        // 0..127
  const int lane = t & 63, w = t >> 6; // 2 waves
  const int quad = lane >> 4, c16 = lane & 15;
  const int sw   = c16 & 7;            // swizzle key for all fragment reads
  const int qt = blockIdx.x, h = blockIdx.y, b = blockIdx.z;
  const size_t bh = (size_t)(b * 16 + h);
  const int qbase = qt * 64 + w * 32;  // this wave's first q-row

  // Q fragments (pre-scaled by 0.125 at qkv time): B-frag of QK^T
  bf16_8 aq[2][2];
#pragma unroll
  for (int mi = 0; mi < 2; ++mi) {
    const __bf16* qptr = Qg + (bh * 2048 + qbase + mi * 16 + c16) * 64;
    aq[mi][0] = *(const bf16_8*)(qptr + quad * 8);
    aq[mi][1] = *(const bf16_8*)(qptr + 32 + quad * 8);
  }

  f32x4 o[4][2];                       // O^T: d = dt*16+quad*4+r, q = mi*16+c16
  const f32x4 zero4 = {0.f, 0.f, 0.f, 0.f};
#pragma unroll
  for (int dt = 0; dt < 4; ++dt)
#pragma unroll
    for (int mi = 0; mi < 2; ++mi) o[dt][mi] = zero4;
  float lsum[2] = {0.f, 0.f};

  const __bf16* Kgp = Kg + bh * 2048 * 64;
  const __bf16* Vgp = VTg + bh * 64 * 2048;
  const float LOG2E  = 1.44269504088896f;
  const float SHIFT2 = -17.3123404907f;  // -12 * log2(e)

  for (int kt = 0; kt < 2048; kt += 64) {
    // ---- stage K [key][d] and V^T [d][key], swizzled 16B chunks ----
#pragma unroll
    for (int i = 0; i < 4; ++i) {
      const int c = t * 4 + i;           // 0..511 chunk id
      const int row = c >> 3, ch = c & 7;
      const int dst = row * 64 + (((ch ^ (row & 7))) << 3);
      *(bf16_8*)&Kl[dst] = *(const bf16_8*)&Kgp[(size_t)(kt + row) * 64 + (ch << 3)];
      *(bf16_8*)&Vl[dst] = *(const bf16_8*)&Vgp[(size_t)row * 2048 + kt + (ch << 3)];
    }
    if (t < 64) maskadd[t] = maskg[b * 2048 + kt + t] ? SHIFT2 : -1e30f;
    __syncthreads();

#pragma unroll
    for (int kb = 0; kb < 4; ++kb) {
      // K A-frags: rows = keys kb*16+c16, d-halves at chunks quad, quad+4
      const int krow = (kb * 16 + c16) * 64;
      const bf16_8 kf0 = *(const bf16_8*)&Kl[krow + ((quad ^ sw) << 3)];
      const bf16_8 kf1 = *(const bf16_8*)&Kl[krow + (((quad + 4) ^ sw) << 3)];
      const f32x4 mav = ((const f32x4*)maskadd)[kb * 4 + quad];

      bf16_4 pf[2];
#pragma unroll
      for (int mi = 0; mi < 2; ++mi) {
        f32x4 sf = MFMA16(kf1, aq[mi][1], MFMA16(kf0, aq[mi][0], zero4));
        const float p0 = __builtin_amdgcn_exp2f(fmaf(sf[0], LOG2E, mav[0]));
        const float p1 = __builtin_amdgcn_exp2f(fmaf(sf[1], LOG2E, mav[1]));
        const float p2 = __builtin_amdgcn_exp2f(fmaf(sf[2], LOG2E, mav[2]));
        const float p3 = __builtin_amdgcn_exp2f(fmaf(sf[3], LOG2E, mav[3]));
        lsum[mi] += (p0 + p1) + (p2 + p3);
        bf16_4 pp = {(__bf16)p0, (__bf16)p1, (__bf16)p2, (__bf16)p3};
        pf[mi] = pp;
      }

      // V^T A-frags (b64): row d = dt*16+c16, keys kb*16+quad*4
#pragma unroll
      for (int dt = 0; dt < 4; ++dt) {
        const int drow = (dt * 16 + c16) * 64;
        const bf16_4 vf = *(const bf16_4*)&Vl[drow +
            (((2 * kb + (quad >> 1)) ^ sw) << 3) + ((quad & 1) << 2)];
        o[dt][0] = MFMA_PV(vf, pf[0], o[dt][0]);
        o[dt][1] = MFMA_PV(vf, pf[1], o[dt][1]);
      }
    }
    __syncthreads();
  }

  // ---- l reduction over the 4 lanes of each column group (quads) ----
  float rl[2];
#pragma unroll
  for (int mi = 0; mi < 2; ++mi) {
    float s_ = lsum[mi];
    s_ += __shfl_xor(s_, 16);
    s_ += __shfl_xor(s_, 32);
    rl[mi] = 1.0f / s_;
  }

  // ---- epilogue: normalize + transpose via LDS (K/V tiles now dead) ----
  __bf16* Oe = KV + w * 2304;          // 32 rows x stride 72 bf16 per wave
#pragma unroll
  for (int dt = 0; dt < 4; ++dt)
#pragma unroll
    for (int mi = 0; mi < 2; ++mi)
#pragma unroll
      for (int r = 0; r < 4; ++r)
        Oe[(mi * 16 + c16) * 72 + dt * 16 + quad * 4 + r] =
            (__bf16)(o[dt][mi][r] * rl[mi]);
  __syncthreads();

  const int rq = lane >> 1, hf = lane & 1;   // row 0..31, 32-col half
  const __bf16* src = KV + w * 2304 + rq * 72 + hf * 32;
  __bf16* dst = ctx + ((size_t)b * 2048 + qbase + rq) * 1024 + h * 64 + hf * 32;
#pragma unroll
  for (int j = 0; j < 4; ++j)
    *(bf16_8*)(dst + j * 8) = *(const bf16_8*)(src + j * 8);
}

// ---------------------------------------------------------------------------
// merged f32 -> bf16 converter
// ---------------------------------------------------------------------------
__global__ __launch_bounds__(256)
void cvt_all(const float* __restrict__ q, const float* __restrict__ k,
             const float* __restrict__ v, const float* __restrict__ Wq,
             const float* __restrict__ Wk, const float* __restrict__ Wv,
             const float* __restrict__ Wo,
             __bf16* __restrict__ xq, __bf16* __restrict__ xk,
             __bf16* __restrict__ xv, __bf16* __restrict__ wqb,
             __bf16* __restrict__ wkb, __bf16* __restrict__ wvb,
             __bf16* __restrict__ wob) {
  const int y = blockIdx.y;
  const float* s;
  __bf16* d;
  int n8;
  switch (y) {
    case 0: s = q;  d = xq;  n8 = 524288; break;
    case 1: s = k;  d = xk;  n8 = 524288; break;
    case 2: s = v;  d = xv;  n8 = 524288; break;
    case 3: s = Wq; d = wqb; n8 = 131072; break;
    case 4: s = Wk; d = wkb; n8 = 131072; break;
    case 5: s = Wv; d = wvb; n8 = 131072; break;
    default: s = Wo; d = wob; n8 = 131072; break;
  }
  const int i = blockIdx.x * blockDim.x + threadIdx.x;
  if (i < n8) {
    const float4* sp = (const float4*)s;
    const float4 v0 = sp[i * 2], v1 = sp[i * 2 + 1];
    bf16_8 o;
    o[0] = (__bf16)v0.x; o[1] = (__bf16)v0.y;
    o[2] = (__bf16)v0.z; o[3] = (__bf16)v0.w;
    o[4] = (__bf16)v1.x; o[5] = (__bf16)v1.y;
    o[6] = (__bf16)v1.z; o[7] = (__bf16)v1.w;
    *(bf16_8*)(d + (size_t)i * 8) = o;
  }
}

// ---------------------------------------------------------------------------
extern "C" void kernel_launch(void* const* d_in, const int* in_sizes, int n_in,
                              void* d_out, int out_size, void* d_ws, size_t ws_size,
                              hipStream_t stream) {
  (void)in_sizes; (void)n_in; (void)out_size; (void)ws_size;
  const float* q    = (const float*)d_in[0];
  const float* k    = (const float*)d_in[1];
  const float* v    = (const float*)d_in[2];
  const int*   mask = (const int*)d_in[3];
  const float* Wq = (const float*)d_in[4];
  const float* bq = (const float*)d_in[5];
  const float* Wk = (const float*)d_in[6];
  const float* bk = (const float*)d_in[7];
  const float* Wv = (const float*)d_in[8];
  const float* bv = (const float*)d_in[9];
  const float* Wo = (const float*)d_in[10];
  const float* bo = (const float*)d_in[11];

  char* ws = (char*)d_ws;
  const size_t MB = 1ull << 20;
  __bf16* xq  = (__bf16*)(ws + 0 * MB);
  __bf16* xk  = (__bf16*)(ws + 8 * MB);
  __bf16* xv  = (__bf16*)(ws + 16 * MB);
  __bf16* wqb = (__bf16*)(ws + 24 * MB);
  __bf16* wkb = (__bf16*)(ws + 26 * MB);
  __bf16* wvb = (__bf16*)(ws + 28 * MB);
  __bf16* wob = (__bf16*)(ws + 30 * MB);
  __bf16* Qb  = (__bf16*)(ws + 32 * MB);
  __bf16* Kb  = (__bf16*)(ws + 40 * MB);
  __bf16* VTb = (__bf16*)(ws + 48 * MB);
  __bf16* ctx = (__bf16*)(ws + 56 * MB);

  cvt_all<<<dim3(2048, 7), 256, 0, stream>>>(q, k, v, Wq, Wk, Wv, Wo,
                                             xq, xk, xv, wqb, wkb, wvb, wob);

  qkv_fused<<<dim3(256, 1, 3), 256, 0, stream>>>(xq, xk, xv, wqb, wkb, wvb,
                                                 bq, bk, bv, Qb, Kb, VTb);

  flash_attn<<<dim3(32, 16, 2), 128, 0, stream>>>(Qb, Kb, VTb, mask, ctx);

  out_proj<<<dim3(512), 256, 0, stream>>>(ctx, wob, bo, (float*)d_out);
}

// Round 6
// 268.419 us; speedup vs baseline: 1.0537x; 1.0537x over previous
//
#include <hip/hip_runtime.h>

// ---------------------------------------------------------------------------
// MultiHeadAttention (B=2, S=2048, D=1024, H=16, dk=64) on gfx950
// R6: flash_attn = register-resident fragments straight from GLOBAL (no LDS,
//     no barriers in the K-loop). Keys split across the block's 2 waves
//     (deferred softmax => partials are additive), one 17KB LDS cross-wave
//     reduction at block end. R5's verified S^T / in-register PV math kept.
// qkv_fused / out_proj / cvt_all unchanged from R4/R5.
// ---------------------------------------------------------------------------

typedef __bf16 bf16_8 __attribute__((ext_vector_type(8)));
typedef __bf16 bf16_4 __attribute__((ext_vector_type(4)));
typedef float  f32x4  __attribute__((ext_vector_type(4)));

#define MFMA16(a, b, c) __builtin_amdgcn_mfma_f32_16x16x32_bf16((a), (b), (c), 0, 0, 0)

#if __has_builtin(__builtin_amdgcn_mfma_f32_16x16x16_bf16)
#define MFMA_PV(a, b, c) __builtin_amdgcn_mfma_f32_16x16x16_bf16((a), (b), (c), 0, 0, 0)
#elif __has_builtin(__builtin_amdgcn_mfma_f32_16x16x16bf16_1k)
typedef short s16x4 __attribute__((ext_vector_type(4)));
#define MFMA_PV(a, b, c)                                                  \
  __builtin_amdgcn_mfma_f32_16x16x16bf16_1k(                              \
      __builtin_bit_cast(s16x4, (a)), __builtin_bit_cast(s16x4, (b)), (c), 0, 0, 0)
#else
static __device__ __forceinline__ f32x4 mfma_pv_asm(bf16_4 a, bf16_4 b, f32x4 c) {
  asm volatile("v_mfma_f32_16x16x16_bf16 %0, %1, %2, %0\n\ts_nop 3"
               : "+v"(c) : "v"(a), "v"(b));
  return c;
}
#define MFMA_PV(a, b, c) mfma_pv_asm((a), (b), (c))
#endif

__device__ __forceinline__ void async_ld16(const void* g, void* l) {
  __builtin_amdgcn_global_load_lds(
      (__attribute__((address_space(1))) void*)g,
      (__attribute__((address_space(3))) void*)l, 16, 0, 0);
}

// ---------------------------------------------------------------------------
// 128x128 GEMM core (m97 structure), BK=32, A [MxK] rm, BT [NxK] rm.
// ---------------------------------------------------------------------------
__device__ __forceinline__ void gemm_core_128(
    const __bf16* __restrict__ A, const __bf16* __restrict__ BT, int K,
    int tm, int tn, __bf16* At, __bf16* Bt, f32x4 acc[4][4]) {
  const int tid  = threadIdx.x;
  const int lane = tid & 63;
  const int w    = tid >> 6;
  const int quad = lane >> 4;
  const int c16  = lane & 15;
  const int wm = w >> 1, wn = w & 1;

  const int ch0  = w * 2;
  const int row0 = ch0 * 16 + (lane >> 2);
  const int col0 = (lane & 3) * 8;
  const __bf16* Ag = A  + (size_t)(tm + row0) * K + col0;
  const __bf16* Bg = BT + (size_t)(tn + row0) * K + col0;
  __bf16* Al = At + ch0 * 512;
  __bf16* Bl = Bt + ch0 * 512;
  const size_t rowK16 = (size_t)16 * K;

  for (int kt = 0; kt < K; kt += 32) {
    async_ld16(Ag + kt,          Al);
    async_ld16(Ag + rowK16 + kt, Al + 512);
    async_ld16(Bg + kt,          Bl);
    async_ld16(Bg + rowK16 + kt, Bl + 512);
    __syncthreads();

    bf16_8 af[4], bfr[4];
#pragma unroll
    for (int mi = 0; mi < 4; ++mi)
      af[mi] = *(const bf16_8*)(At + (wm * 64 + mi * 16 + c16) * 32 + quad * 8);
#pragma unroll
    for (int ni = 0; ni < 4; ++ni)
      bfr[ni] = *(const bf16_8*)(Bt + (wn * 64 + ni * 16 + c16) * 32 + quad * 8);
#pragma unroll
    for (int mi = 0; mi < 4; ++mi)
#pragma unroll
      for (int ni = 0; ni < 4; ++ni)
        acc[mi][ni] = MFMA16(af[mi], bfr[ni], acc[mi][ni]);
    __syncthreads();
  }
}

// ---------------------------------------------------------------------------
// Fused QKV projection. grid = (256,1,3). V produced transposed [B,H,64,S].
// Q output pre-scaled by 1/sqrt(dk)=0.125.
// ---------------------------------------------------------------------------
__global__ __launch_bounds__(256)
void qkv_fused(const __bf16* __restrict__ xq, const __bf16* __restrict__ xk,
               const __bf16* __restrict__ xv,
               const __bf16* __restrict__ wq, const __bf16* __restrict__ wk,
               const __bf16* __restrict__ wv,
               const float* __restrict__ bq, const float* __restrict__ bk,
               const float* __restrict__ bv,
               __bf16* __restrict__ Qo, __bf16* __restrict__ Ko,
               __bf16* __restrict__ Vo) {
  __shared__ __bf16 At[128 * 32];
  __shared__ __bf16 Bt[128 * 32];
  const int z  = blockIdx.z;
  const int bx = blockIdx.x;
  const __bf16 *A, *BT;
  const float* bias;
  int tm, tn;
  if (z == 2) {        // V^T: M=1024 feats, N=4096 tokens
    A = wv; BT = xv; bias = bv;
    tm = (bx >> 5) * 128; tn = (bx & 31) * 128;
  } else if (z == 1) {
    A = xk; BT = wk; bias = bk;
    tm = (bx >> 3) * 128; tn = (bx & 7) * 128;
  } else {
    A = xq; BT = wq; bias = bq;
    tm = (bx >> 3) * 128; tn = (bx & 7) * 128;
  }

  f32x4 acc[4][4];
  const f32x4 zero4 = {0.f, 0.f, 0.f, 0.f};
#pragma unroll
  for (int i = 0; i < 4; ++i)
#pragma unroll
    for (int j = 0; j < 4; ++j) acc[i][j] = zero4;

  gemm_core_128(A, BT, 1024, tm, tn, At, Bt, acc);

  const int lane = threadIdx.x & 63;
  const int w    = threadIdx.x >> 6;
  const int quad = lane >> 4, c16 = lane & 15;
  const int wm = w >> 1, wn = w & 1;

  if (z == 2) {
#pragma unroll
    for (int mi = 0; mi < 4; ++mi) {
#pragma unroll
      for (int ni = 0; ni < 4; ++ni) {
        const int n  = tn + wn * 64 + ni * 16 + c16;  // token
        const int bb = n >> 11, s = n & 2047;
#pragma unroll
        for (int r = 0; r < 4; ++r) {
          const int m  = tm + wm * 64 + mi * 16 + quad * 4 + r;  // feature
          const int hh = m >> 6, d = m & 63;
          Vo[(((size_t)(bb * 16 + hh) * 64 + d) << 11) + s] =
              (__bf16)(acc[mi][ni][r] + bias[m]);
        }
      }
    }
  } else {
    __bf16* Out = (z == 1) ? Ko : Qo;
    const float scale = (z == 0) ? 0.125f : 1.0f;
#pragma unroll
    for (int mi = 0; mi < 4; ++mi) {
#pragma unroll
      for (int ni = 0; ni < 4; ++ni) {
        const int n  = tn + wn * 64 + ni * 16 + c16;  // feature
        const int hh = n >> 6, d = n & 63;
        const float bn = bias[n];
#pragma unroll
        for (int r = 0; r < 4; ++r) {
          const int m  = tm + wm * 64 + mi * 16 + quad * 4 + r;  // token
          const int bb = m >> 11, s = m & 2047;
          Out[(((size_t)(bb * 16 + hh) * 2048 + s) << 6) + d] =
              (__bf16)((acc[mi][ni][r] + bn) * scale);
        }
      }
    }
  }
}

// ---------------------------------------------------------------------------
// Output projection, 64x128 tile -> 512 blocks.
// ---------------------------------------------------------------------------
__global__ __launch_bounds__(256)
void out_proj(const __bf16* __restrict__ ctx, const __bf16* __restrict__ wo,
              const float* __restrict__ bo, float* __restrict__ out) {
  __shared__ __bf16 At[64 * 32];
  __shared__ __bf16 Bt[128 * 32];
  const int bx = blockIdx.x;
  const int tm = (bx >> 3) * 64, tn = (bx & 7) * 128;

  const int tid  = threadIdx.x;
  const int lane = tid & 63, w = tid >> 6;
  const int quad = lane >> 4, c16 = lane & 15;
  const int wm = w >> 1, wn = w & 1;

  const int row0 = lane >> 2, col0 = (lane & 3) * 8;
  const __bf16* Ag = ctx + (size_t)(tm + w * 16 + row0) * 1024 + col0;
  const __bf16* Bg = wo  + (size_t)(tn + w * 32 + row0) * 1024 + col0;
  __bf16* Al = At + w * 512;
  __bf16* Bl = Bt + w * 1024;

  f32x4 acc[2][4];
  const f32x4 zero4 = {0.f, 0.f, 0.f, 0.f};
#pragma unroll
  for (int i = 0; i < 2; ++i)
#pragma unroll
    for (int j = 0; j < 4; ++j) acc[i][j] = zero4;

  for (int kt = 0; kt < 1024; kt += 32) {
    async_ld16(Ag + kt, Al);
    async_ld16(Bg + kt, Bl);
    async_ld16(Bg + 16 * 1024 + kt, Bl + 512);
    __syncthreads();

    bf16_8 af[2], bfr[4];
#pragma unroll
    for (int mi = 0; mi < 2; ++mi)
      af[mi] = *(const bf16_8*)(At + (wm * 32 + mi * 16 + c16) * 32 + quad * 8);
#pragma unroll
    for (int ni = 0; ni < 4; ++ni)
      bfr[ni] = *(const bf16_8*)(Bt + (wn * 64 + ni * 16 + c16) * 32 + quad * 8);
#pragma unroll
    for (int mi = 0; mi < 2; ++mi)
#pragma unroll
      for (int ni = 0; ni < 4; ++ni)
        acc[mi][ni] = MFMA16(af[mi], bfr[ni], acc[mi][ni]);
    __syncthreads();
  }

#pragma unroll
  for (int mi = 0; mi < 2; ++mi) {
#pragma unroll
    for (int ni = 0; ni < 4; ++ni) {
      const int n = tn + wn * 64 + ni * 16 + c16;
      const float bn = bo[n];
#pragma unroll
      for (int r = 0; r < 4; ++r) {
        const int m = tm + wm * 32 + mi * 16 + quad * 4 + r;
        out[(size_t)m * 1024 + n] = acc[mi][ni][r] + bn;
      }
    }
  }
}

// ---------------------------------------------------------------------------
// Flash attention R6. grid = (32 q-tiles, 16 h, 2 b), 128 threads (2 waves).
// Block = 64 q-rows; wave w owns keys [w*1024, w*1024+1024) (16 iters of 64).
// All fragments straight from global (K rows -> 16x64B line requests; V^T
// rows -> dwordx2; Q loaded once). NO LDS / barriers in the loop.
// S^T = K·Q^T (A=K,B=Q) -> D[key=quad*4+r][q=c16]; p packed bf16x4 is the
// B-frag of mfma_16x16x16; O^T[d][q] += V^T-frag · p  (all verified in R5).
// Deferred softmax (fixed -12 shift in log2 domain); cross-wave combine of
// (O^T, l) via 17KB LDS once at the end; wave0 normalizes + stores ctx.
// ---------------------------------------------------------------------------
__global__ __launch_bounds__(128, 2)
void flash_attn(const __bf16* __restrict__ Qg, const __bf16* __restrict__ Kg,
                const __bf16* __restrict__ VTg, const int* __restrict__ maskg,
                __bf16* __restrict__ ctx) {
  __shared__ float Ored[64 * 68];
  __shared__ float lred[64];

  const int t    = threadIdx.x;
  const int lane = t & 63, w = t >> 6;
  const int quad = lane >> 4, c16 = lane & 15;
  const int qt = blockIdx.x, h = blockIdx.y, b = blockIdx.z;
  const size_t bh = (size_t)(b * 16 + h);
  const int qbase = qt * 64;

  // Q B-frags (pre-scaled by 0.125 at qkv time), 4 q-subtiles x 2 d-halves
  bf16_8 aq[4][2];
#pragma unroll
  for (int qi = 0; qi < 4; ++qi) {
    const __bf16* qptr = Qg + (bh * 2048 + qbase + qi * 16 + c16) * 64;
    aq[qi][0] = *(const bf16_8*)(qptr + quad * 8);
    aq[qi][1] = *(const bf16_8*)(qptr + 32 + quad * 8);
  }

  f32x4 o[4][4];                    // [dt][qi]: O^T[d=dt*16+quad*4+r][q=qi*16+c16]
  const f32x4 zero4 = {0.f, 0.f, 0.f, 0.f};
#pragma unroll
  for (int dt = 0; dt < 4; ++dt)
#pragma unroll
    for (int qi = 0; qi < 4; ++qi) o[dt][qi] = zero4;
  float lsum[4] = {0.f, 0.f, 0.f, 0.f};

  const __bf16* Kgp = Kg + bh * 2048 * 64;
  const __bf16* Vgp = VTg + bh * 64 * 2048;
  const int*    mgp = maskg + b * 2048;
  const float LOG2E  = 1.44269504088896f;
  const float SHIFT2 = -17.3123404907f;   // -12 * log2(e)

  const int k0 = w * 1024;
  for (int kt = k0; kt < k0 + 1024; kt += 64) {
#pragma unroll
    for (int kb = 0; kb < 4; ++kb) {
      const int key0 = kt + kb * 16;
      // K A-frag: 16 keys x 32 d per half, each load = 16 full 64B lines
      const bf16_8 kf0 = *(const bf16_8*)&Kgp[(size_t)(key0 + c16) * 64 + quad * 8];
      const bf16_8 kf1 = *(const bf16_8*)&Kgp[(size_t)(key0 + c16) * 64 + 32 + quad * 8];
      const int4 mi4 = *(const int4*)&mgp[key0 + quad * 4];
      const float ma0 = mi4.x ? SHIFT2 : -1e30f;
      const float ma1 = mi4.y ? SHIFT2 : -1e30f;
      const float ma2 = mi4.z ? SHIFT2 : -1e30f;
      const float ma3 = mi4.w ? SHIFT2 : -1e30f;

      bf16_4 pf[4];
#pragma unroll
      for (int qi = 0; qi < 4; ++qi) {
        f32x4 sf = MFMA16(kf1, aq[qi][1], MFMA16(kf0, aq[qi][0], zero4));
        const float p0 = __builtin_amdgcn_exp2f(fmaf(sf[0], LOG2E, ma0));
        const float p1 = __builtin_amdgcn_exp2f(fmaf(sf[1], LOG2E, ma1));
        const float p2 = __builtin_amdgcn_exp2f(fmaf(sf[2], LOG2E, ma2));
        const float p3 = __builtin_amdgcn_exp2f(fmaf(sf[3], LOG2E, ma3));
        lsum[qi] += (p0 + p1) + (p2 + p3);
        bf16_4 pp = {(__bf16)p0, (__bf16)p1, (__bf16)p2, (__bf16)p3};
        pf[qi] = pp;
      }

      // V^T A-frag: row d, 4 keys (k=quad*4+j); reused across all 4 qi
#pragma unroll
      for (int dt = 0; dt < 4; ++dt) {
        const bf16_4 vf =
            *(const bf16_4*)&Vgp[(size_t)(dt * 16 + c16) * 2048 + key0 + quad * 4];
        o[dt][0] = MFMA_PV(vf, pf[0], o[dt][0]);
        o[dt][1] = MFMA_PV(vf, pf[1], o[dt][1]);
        o[dt][2] = MFMA_PV(vf, pf[2], o[dt][2]);
        o[dt][3] = MFMA_PV(vf, pf[3], o[dt][3]);
      }
    }
  }

  // per-wave l: reduce over the 4 quads (keys quad*4+r)
#pragma unroll
  for (int qi = 0; qi < 4; ++qi) {
    float s_ = lsum[qi];
    s_ += __shfl_xor(s_, 16);
    s_ += __shfl_xor(s_, 32);
    lsum[qi] = s_;
  }

  // cross-wave combine: wave1 publishes partials, wave0 merges
  if (w == 1) {
#pragma unroll
    for (int dt = 0; dt < 4; ++dt)
#pragma unroll
      for (int qi = 0; qi < 4; ++qi)
        *(f32x4*)&Ored[(qi * 16 + c16) * 68 + dt * 16 + quad * 4] = o[dt][qi];
    if (quad == 0) {
#pragma unroll
      for (int qi = 0; qi < 4; ++qi) lred[qi * 16 + c16] = lsum[qi];
    }
  }
  __syncthreads();
  if (w == 1) return;

  float rl[4];
#pragma unroll
  for (int qi = 0; qi < 4; ++qi)
    rl[qi] = 1.0f / (lsum[qi] + lred[qi * 16 + c16]);
#pragma unroll
  for (int dt = 0; dt < 4; ++dt)
#pragma unroll
    for (int qi = 0; qi < 4; ++qi)
      o[dt][qi] += *(const f32x4*)&Ored[(qi * 16 + c16) * 68 + dt * 16 + quad * 4];

  // normalize + transpose via LDS (reuse Ored as bf16), then coalesced store
  __bf16* Oe = (__bf16*)Ored;
#pragma unroll
  for (int dt = 0; dt < 4; ++dt) {
#pragma unroll
    for (int qi = 0; qi < 4; ++qi) {
      bf16_4 ob = {(__bf16)(o[dt][qi][0] * rl[qi]), (__bf16)(o[dt][qi][1] * rl[qi]),
                   (__bf16)(o[dt][qi][2] * rl[qi]), (__bf16)(o[dt][qi][3] * rl[qi])};
      *(bf16_4*)&Oe[(qi * 16 + c16) * 72 + dt * 16 + quad * 4] = ob;
    }
  }
  // 8 lanes per q-row -> full-row coalesced 16B stores
  const int rr = lane >> 3, cc = lane & 7;
#pragma unroll
  for (int i = 0; i < 8; ++i) {
    const int q = i * 8 + rr;
    const bf16_8 val = *(const bf16_8*)&Oe[q * 72 + cc * 8];
    *(bf16_8*)&ctx[((size_t)b * 2048 + qbase + q) * 1024 + h * 64 + cc * 8] = val;
  }
}

// ---------------------------------------------------------------------------
// merged f32 -> bf16 converter
// ---------------------------------------------------------------------------
__global__ __launch_bounds__(256)
void cvt_all(const float* __restrict__ q, const float* __restrict__ k,
             const float* __restrict__ v, const float* __restrict__ Wq,
             const float* __restrict__ Wk, const float* __restrict__ Wv,
             const float* __restrict__ Wo,
             __bf16* __restrict__ xq, __bf16* __restrict__ xk,
             __bf16* __restrict__ xv, __bf16* __restrict__ wqb,
             __bf16* __restrict__ wkb, __bf16* __restrict__ wvb,
             __bf16* __restrict__ wob) {
  const int y = blockIdx.y;
  const float* s;
  __bf16* d;
  int n8;
  switch (y) {
    case 0: s = q;  d = xq;  n8 = 524288; break;
    case 1: s = k;  d = xk;  n8 = 524288; break;
    case 2: s = v;  d = xv;  n8 = 524288; break;
    case 3: s = Wq; d = wqb; n8 = 131072; break;
    case 4: s = Wk; d = wkb; n8 = 131072; break;
    case 5: s = Wv; d = wvb; n8 = 131072; break;
    default: s = Wo; d = wob; n8 = 131072; break;
  }
  const int i = blockIdx.x * blockDim.x + threadIdx.x;
  if (i < n8) {
    const float4* sp = (const float4*)s;
    const float4 v0 = sp[i * 2], v1 = sp[i * 2 + 1];
    bf16_8 o;
    o[0] = (__bf16)v0.x; o[1] = (__bf16)v0.y;
    o[2] = (__bf16)v0.z; o[3] = (__bf16)v0.w;
    o[4] = (__bf16)v1.x; o[5] = (__bf16)v1.y;
    o[6] = (__bf16)v1.z; o[7] = (__bf16)v1.w;
    *(bf16_8*)(d + (size_t)i * 8) = o;
  }
}

// ---------------------------------------------------------------------------
extern "C" void kernel_launch(void* const* d_in, const int* in_sizes, int n_in,
                              void* d_out, int out_size, void* d_ws, size_t ws_size,
                              hipStream_t stream) {
  (void)in_sizes; (void)n_in; (void)out_size; (void)ws_size;
  const float* q    = (const float*)d_in[0];
  const float* k    = (const float*)d_in[1];
  const float* v    = (const float*)d_in[2];
  const int*   mask = (const int*)d_in[3];
  const float* Wq = (const float*)d_in[4];
  const float* bq = (const float*)d_in[5];
  const float* Wk = (const float*)d_in[6];
  const float* bk = (const float*)d_in[7];
  const float* Wv = (const float*)d_in[8];
  const float* bv = (const float*)d_in[9];
  const float* Wo = (const float*)d_in[10];
  const float* bo = (const float*)d_in[11];

  char* ws = (char*)d_ws;
  const size_t MB = 1ull << 20;
  __bf16* xq  = (__bf16*)(ws + 0 * MB);
  __bf16* xk  = (__bf16*)(ws + 8 * MB);
  __bf16* xv  = (__bf16*)(ws + 16 * MB);
  __bf16* wqb = (__bf16*)(ws + 24 * MB);
  __bf16* wkb = (__bf16*)(ws + 26 * MB);
  __bf16* wvb = (__bf16*)(ws + 28 * MB);
  __bf16* wob = (__bf16*)(ws + 30 * MB);
  __bf16* Qb  = (__bf16*)(ws + 32 * MB);
  __bf16* Kb  = (__bf16*)(ws + 40 * MB);
  __bf16* VTb = (__bf16*)(ws + 48 * MB);
  __bf16* ctx = (__bf16*)(ws + 56 * MB);

  cvt_all<<<dim3(2048, 7), 256, 0, stream>>>(q, k, v, Wq, Wk, Wv, Wo,
                                             xq, xk, xv, wqb, wkb, wvb, wob);

  qkv_fused<<<dim3(256, 1, 3), 256, 0, stream>>>(xq, xk, xv, wqb, wkb, wvb,
                                                 bq, bk, bv, Qb, Kb, VTb);

  flash_attn<<<dim3(32, 16, 2), 128, 0, stream>>>(Qb, Kb, VTb, mask, ctx);

  out_proj<<<dim3(512), 256, 0, stream>>>(ctx, wob, bo, (float*)d_out);
}